// Round 1
// baseline (197.656 us; speedup 1.0000x reference)
//
#include <hip/hip_runtime.h>

#define BB 2
#define NN 2048
#define DD 512
#define HH 8
#define DK 64

typedef __attribute__((ext_vector_type(4))) float f32x4;
typedef __attribute__((ext_vector_type(8))) short bf16x8;

__device__ __forceinline__ short f2bf(float f) {
  union { float f; unsigned u; } v; v.f = f;
  unsigned r = v.u + 0x7fffu + ((v.u >> 16) & 1u);
  return (short)(r >> 16);
}

__device__ __forceinline__ bf16x8 pack8(float4 a, float4 b) {
  bf16x8 r;
  r[0] = f2bf(a.x); r[1] = f2bf(a.y); r[2] = f2bf(a.z); r[3] = f2bf(a.w);
  r[4] = f2bf(b.x); r[5] = f2bf(b.y); r[6] = f2bf(b.z); r[7] = f2bf(b.w);
  return r;
}

// ---------------------------------------------------------------------------
// GEMM1: [Q|K|V] = X @ W^T + b   (M=4096, N=1536, K=512), bf16 MFMA.
// Q,K written (B,H,N,DK) row-major; V written transposed (B,H,DK,N).
// ---------------------------------------------------------------------------
__global__ __launch_bounds__(256) void qkv_gemm(
    const float* __restrict__ X,
    const float* __restrict__ wq, const float* __restrict__ wk, const float* __restrict__ wv,
    const float* __restrict__ bq, const float* __restrict__ bk, const float* __restrict__ bv,
    short* __restrict__ qo, short* __restrict__ ko, short* __restrict__ vto)
{
  __shared__ alignas(16) short Xs[64][40];
  __shared__ alignas(16) short Ws[64][40];

  const int tid = threadIdx.x;
  const int m0 = (blockIdx.x & 63) * 64;
  const int nt = blockIdx.x >> 6;        // 0..23
  const int n0g = nt * 64;
  const int sel = n0g >> 9;              // 0=Q 1=K 2=V
  const int nw = n0g & 511;
  const float* Wm = sel == 0 ? wq : (sel == 1 ? wk : wv);
  const float* bias = sel == 0 ? bq : (sel == 1 ? bk : bv);

  const int lrow = tid >> 2;
  const int lcol = (tid & 3) * 8;
  const int wv_ = tid >> 6;
  const int lane = tid & 63;
  const int q4 = lane >> 4;
  const int c = lane & 15;

  f32x4 acc[4];
#pragma unroll
  for (int i = 0; i < 4; i++) acc[i] = f32x4{0.f, 0.f, 0.f, 0.f};

  for (int k0 = 0; k0 < DD; k0 += 32) {
    __syncthreads();
    {
      const float* xp = X + (size_t)(m0 + lrow) * DD + k0 + lcol;
      float4 x0 = *(const float4*)xp;
      float4 x1 = *(const float4*)(xp + 4);
      *(bf16x8*)&Xs[lrow][lcol] = pack8(x0, x1);
      const float* wp = Wm + (size_t)(nw + lrow) * DD + k0 + lcol;
      float4 w0 = *(const float4*)wp;
      float4 w1 = *(const float4*)(wp + 4);
      *(bf16x8*)&Ws[lrow][lcol] = pack8(w0, w1);
    }
    __syncthreads();
    bf16x8 af = *(const bf16x8*)&Xs[16 * wv_ + c][q4 * 8];
#pragma unroll
    for (int ns = 0; ns < 4; ns++) {
      bf16x8 bf = *(const bf16x8*)&Ws[ns * 16 + c][q4 * 8];
      acc[ns] = __builtin_amdgcn_mfma_f32_16x16x32_bf16(af, bf, acc[ns], 0, 0, 0);
    }
  }

#pragma unroll
  for (int ns = 0; ns < 4; ns++) {
    const int n = nw + ns * 16 + c;
    const float bval = bias[n];
    const int hh = n >> 6, d = n & 63;
#pragma unroll
    for (int r = 0; r < 4; r++) {
      const int m = m0 + 16 * wv_ + q4 * 4 + r;
      const int bb = m >> 11, tok = m & 2047;
      const float val = acc[ns][r] + bval;
      if (sel == 2)      vto[((size_t)(bb * HH + hh) * DK + d) * NN + tok] = f2bf(val);
      else if (sel == 1) ko [((size_t)(bb * HH + hh) * NN + tok) * DK + d] = f2bf(val);
      else               qo [((size_t)(bb * HH + hh) * NN + tok) * DK + d] = f2bf(val);
    }
  }
}

// ---------------------------------------------------------------------------
// Flash attention with graph mask + temporal bias.
// Block = 4 waves = 4 heads sharing one 32-row query tile; loops j in 64-tiles.
// adj/edge_times tile staged once per block (shared by 4 heads).
// ---------------------------------------------------------------------------
__global__ __launch_bounds__(256) void attn_kernel(
    const short* __restrict__ qt, const short* __restrict__ kt, const short* __restrict__ vtt,
    const int* __restrict__ adj, const float* __restrict__ et,
    const int* __restrict__ ctp, const float* __restrict__ wt, const float* __restrict__ bt,
    short* __restrict__ ao)
{
  __shared__ float tws[32][65];               // masked temporal weight (mask -> -1)
  __shared__ alignas(16) short Ps[4][32][72]; // per-wave P (bf16), padded stride

  const int tid = threadIdx.x;
  const int lane = tid & 63;
  const int w = tid >> 6;
  const int q4 = lane >> 4;
  const int c = lane & 15;

  const int bid = blockIdx.x;
  const int b = bid >> 7;
  const int it = (bid & 127) >> 1;
  const int hg = bid & 1;
  const int h = hg * 4 + w;
  const int i0 = it * 32;

  const float ct = (float)(*ctp);
  const float wth = wt[h];
  const float bth = bt[h];

  const short* qb = qt + ((size_t)(b * HH + h) * NN + i0) * DK;
  const short* kb = kt + (size_t)(b * HH + h) * NN * DK;
  const short* vb = vtt + (size_t)(b * HH + h) * DK * NN;
  const int* adjb = adj + (size_t)(b * NN + i0) * NN;
  const float* etb = et + (size_t)(b * NN + i0) * NN;

  // Q fragments (held for the whole j loop)
  bf16x8 aq[2][2];
#pragma unroll
  for (int is = 0; is < 2; is++)
#pragma unroll
    for (int ks = 0; ks < 2; ks++)
      aq[is][ks] = *(const bf16x8*)(qb + (is * 16 + c) * DK + ks * 32 + q4 * 8);

  float m_[2][4], l_[2][4];
  f32x4 o[2][4];
#pragma unroll
  for (int is = 0; is < 2; is++)
#pragma unroll
    for (int r = 0; r < 4; r++) { m_[is][r] = -3.0e38f; l_[is][r] = 0.f; }
#pragma unroll
  for (int is = 0; is < 2; is++)
#pragma unroll
    for (int ds = 0; ds < 4; ds++) o[is][ds] = f32x4{0.f, 0.f, 0.f, 0.f};

  const int sr = tid >> 3;
  const int sc = (tid & 7) * 8;

  for (int j0 = 0; j0 < NN; j0 += 64) {
    __syncthreads();
    {
      const int* ap = adjb + (size_t)sr * NN + j0 + sc;
      const float* ep = etb + (size_t)sr * NN + j0 + sc;
      int4 a0 = *(const int4*)ap;
      int4 a1 = *(const int4*)(ap + 4);
      float4 e0 = *(const float4*)ep;
      float4 e1 = *(const float4*)(ep + 4);
      const int av[8] = {a0.x, a0.y, a0.z, a0.w, a1.x, a1.y, a1.z, a1.w};
      const float ev[8] = {e0.x, e0.y, e0.z, e0.w, e1.x, e1.y, e1.z, e1.w};
#pragma unroll
      for (int i = 0; i < 8; i++) {
        float tv = (av[i] == 0) ? -1.f : __expf(-0.1f * fmaxf(ct - ev[i], 0.f));
        tws[sr][sc + i] = tv;
      }
    }
    __syncthreads();

    // S = Q K^T
    f32x4 s[2][4];
#pragma unroll
    for (int is = 0; is < 2; is++)
#pragma unroll
      for (int js = 0; js < 4; js++) s[is][js] = f32x4{0.f, 0.f, 0.f, 0.f};
#pragma unroll
    for (int ks = 0; ks < 2; ks++) {
      bf16x8 bk[4];
#pragma unroll
      for (int js = 0; js < 4; js++)
        bk[js] = *(const bf16x8*)(kb + (size_t)(j0 + js * 16 + c) * DK + ks * 32 + q4 * 8);
#pragma unroll
      for (int is = 0; is < 2; is++)
#pragma unroll
        for (int js = 0; js < 4; js++)
          s[is][js] = __builtin_amdgcn_mfma_f32_16x16x32_bf16(aq[is][ks], bk[js], s[is][js], 0, 0, 0);
    }

    // scale + mask + temporal bias; track tile row max
    float tmax[2][4];
#pragma unroll
    for (int is = 0; is < 2; is++)
#pragma unroll
      for (int r = 0; r < 4; r++) tmax[is][r] = -3.0e38f;
#pragma unroll
    for (int is = 0; is < 2; is++)
#pragma unroll
      for (int js = 0; js < 4; js++)
#pragma unroll
        for (int r = 0; r < 4; r++) {
          const int row = is * 16 + q4 * 4 + r;
          const float t = tws[row][js * 16 + c];
          float sv = s[is][js][r];
          sv = (t < 0.f) ? -3.0e38f : sv * 0.125f + t * wth + bth;
          s[is][js][r] = sv;
          tmax[is][r] = fmaxf(tmax[is][r], sv);
        }
#pragma unroll
    for (int is = 0; is < 2; is++)
#pragma unroll
      for (int r = 0; r < 4; r++) {
#pragma unroll
        for (int off = 1; off < 16; off <<= 1)
          tmax[is][r] = fmaxf(tmax[is][r], __shfl_xor(tmax[is][r], off));
      }

    // online softmax update
    float corr[2][4], psum[2][4];
#pragma unroll
    for (int is = 0; is < 2; is++)
#pragma unroll
      for (int r = 0; r < 4; r++) {
        const float mn = fmaxf(m_[is][r], tmax[is][r]);
        corr[is][r] = __expf(m_[is][r] - mn);  // both -3e38 -> exp(0)=1; old -inf-ish -> 0
        m_[is][r] = mn;
        psum[is][r] = 0.f;
      }
#pragma unroll
    for (int is = 0; is < 2; is++)
#pragma unroll
      for (int js = 0; js < 4; js++)
#pragma unroll
        for (int r = 0; r < 4; r++) {
          const float p = __expf(s[is][js][r] - m_[is][r]);
          psum[is][r] += p;
          Ps[w][is * 16 + q4 * 4 + r][js * 16 + c] = f2bf(p);
        }
#pragma unroll
    for (int is = 0; is < 2; is++)
#pragma unroll
      for (int r = 0; r < 4; r++) {
#pragma unroll
        for (int off = 1; off < 16; off <<= 1)
          psum[is][r] += __shfl_xor(psum[is][r], off);
        l_[is][r] = l_[is][r] * corr[is][r] + psum[is][r];
      }
#pragma unroll
    for (int is = 0; is < 2; is++)
#pragma unroll
      for (int ds = 0; ds < 4; ds++)
#pragma unroll
        for (int r = 0; r < 4; r++) o[is][ds][r] *= corr[is][r];

    // O += P V   (P from per-wave LDS, V^T from global: contiguous 16B frags)
#pragma unroll
    for (int ks = 0; ks < 2; ks++) {
      bf16x8 pa[2];
#pragma unroll
      for (int is = 0; is < 2; is++)
        pa[is] = *(const bf16x8*)&Ps[w][is * 16 + c][ks * 32 + q4 * 8];
      bf16x8 bv[4];
#pragma unroll
      for (int ds = 0; ds < 4; ds++)
        bv[ds] = *(const bf16x8*)(vb + (size_t)(ds * 16 + c) * NN + j0 + ks * 32 + q4 * 8);
#pragma unroll
      for (int is = 0; is < 2; is++)
#pragma unroll
        for (int ds = 0; ds < 4; ds++)
          o[is][ds] = __builtin_amdgcn_mfma_f32_16x16x32_bf16(pa[is], bv[ds], o[is][ds], 0, 0, 0);
    }
  }

  // epilogue: AO[b][tok][h*64+d] bf16
#pragma unroll
  for (int is = 0; is < 2; is++)
#pragma unroll
    for (int ds = 0; ds < 4; ds++)
#pragma unroll
      for (int r = 0; r < 4; r++) {
        const int row = i0 + is * 16 + q4 * 4 + r;
        const float val = o[is][ds][r] / l_[is][r];
        ao[(size_t)(b * NN + row) * DD + h * DK + ds * 16 + c] = f2bf(val);
      }
}

// ---------------------------------------------------------------------------
// GEMM2: out = AO @ wo^T + bo + node_features   (M=4096, N=512, K=512)
// ---------------------------------------------------------------------------
__global__ __launch_bounds__(256) void out_gemm(
    const short* __restrict__ AO, const float* __restrict__ wo, const float* __restrict__ bo,
    const float* __restrict__ nf, float* __restrict__ out)
{
  __shared__ alignas(16) short As[64][40];
  __shared__ alignas(16) short Ws[64][40];

  const int tid = threadIdx.x;
  const int m0 = (blockIdx.x & 63) * 64;
  const int n0 = (blockIdx.x >> 6) * 64;

  const int lrow = tid >> 2;
  const int lcol = (tid & 3) * 8;
  const int wv_ = tid >> 6;
  const int lane = tid & 63;
  const int q4 = lane >> 4;
  const int c = lane & 15;

  f32x4 acc[4];
#pragma unroll
  for (int i = 0; i < 4; i++) acc[i] = f32x4{0.f, 0.f, 0.f, 0.f};

  for (int k0 = 0; k0 < DD; k0 += 32) {
    __syncthreads();
    {
      bf16x8 av = *(const bf16x8*)(AO + (size_t)(m0 + lrow) * DD + k0 + lcol);
      *(bf16x8*)&As[lrow][lcol] = av;
      const float* wp = wo + (size_t)(n0 + lrow) * DD + k0 + lcol;
      float4 w0 = *(const float4*)wp;
      float4 w1 = *(const float4*)(wp + 4);
      *(bf16x8*)&Ws[lrow][lcol] = pack8(w0, w1);
    }
    __syncthreads();
    bf16x8 af = *(const bf16x8*)&As[16 * wv_ + c][q4 * 8];
#pragma unroll
    for (int ns = 0; ns < 4; ns++) {
      bf16x8 bf = *(const bf16x8*)&Ws[ns * 16 + c][q4 * 8];
      acc[ns] = __builtin_amdgcn_mfma_f32_16x16x32_bf16(af, bf, acc[ns], 0, 0, 0);
    }
  }

#pragma unroll
  for (int ns = 0; ns < 4; ns++) {
    const int n = n0 + ns * 16 + c;
    const float bval = bo[n];
#pragma unroll
    for (int r = 0; r < 4; r++) {
      const int m = m0 + 16 * wv_ + q4 * 4 + r;
      out[(size_t)m * DD + n] = acc[ns][r] + bval + nf[(size_t)m * DD + n];
    }
  }
}

extern "C" void kernel_launch(void* const* d_in, const int* in_sizes, int n_in,
                              void* d_out, int out_size, void* d_ws, size_t ws_size,
                              hipStream_t stream) {
  const float* nf  = (const float*)d_in[0];
  const int*   adj = (const int*)d_in[1];
  const float* et  = (const float*)d_in[2];
  const int*   ct  = (const int*)d_in[3];
  const float* wq  = (const float*)d_in[4];
  const float* bq  = (const float*)d_in[5];
  const float* wk  = (const float*)d_in[6];
  const float* bk  = (const float*)d_in[7];
  const float* wv  = (const float*)d_in[8];
  const float* bv  = (const float*)d_in[9];
  const float* wo  = (const float*)d_in[10];
  const float* bo  = (const float*)d_in[11];
  const float* wt  = (const float*)d_in[12];
  const float* bt  = (const float*)d_in[13];

  const size_t SZ = (size_t)BB * HH * NN * DK;  // 2,097,152 elements
  short* q  = (short*)d_ws;
  short* k  = q + SZ;
  short* vt = k + SZ;
  short* ao = vt + SZ;

  qkv_gemm<<<1536, 256, 0, stream>>>(nf, wq, wk, wv, bq, bk, bv, q, k, vt);
  attn_kernel<<<256, 256, 0, stream>>>(q, k, vt, adj, et, ct, wt, bt, ao);
  out_gemm<<<512, 256, 0, stream>>>(ao, wo, bo, nf, (float*)d_out);
}

// Round 2
// 196.600 us; speedup vs baseline: 1.0054x; 1.0054x over previous
//
#include <hip/hip_runtime.h>

#define BB 2
#define NN 2048
#define DD 512
#define HH 8
#define DK 64

typedef __attribute__((ext_vector_type(4))) float f32x4;
typedef __attribute__((ext_vector_type(8))) short bf16x8;

__device__ __forceinline__ short f2bf(float f) {
  union { float f; unsigned u; } v; v.f = f;
  unsigned r = v.u + 0x7fffu + ((v.u >> 16) & 1u);
  return (short)(r >> 16);
}

__device__ __forceinline__ bf16x8 pack8(float4 a, float4 b) {
  bf16x8 r;
  r[0] = f2bf(a.x); r[1] = f2bf(a.y); r[2] = f2bf(a.z); r[3] = f2bf(a.w);
  r[4] = f2bf(b.x); r[5] = f2bf(b.y); r[6] = f2bf(b.z); r[7] = f2bf(b.w);
  return r;
}

// ---------------------------------------------------------------------------
// GEMM1: [Q|K|V] = X @ W^T + b   (M=4096, N=1536, K=512), bf16 MFMA.
// Q,K written (B,H,N,DK) row-major; V written transposed (B,H,DK,N).
// ---------------------------------------------------------------------------
__global__ __launch_bounds__(256) void qkv_gemm(
    const float* __restrict__ X,
    const float* __restrict__ wq, const float* __restrict__ wk, const float* __restrict__ wv,
    const float* __restrict__ bq, const float* __restrict__ bk, const float* __restrict__ bv,
    short* __restrict__ qo, short* __restrict__ ko, short* __restrict__ vto)
{
  __shared__ alignas(16) short Xs[64][40];
  __shared__ alignas(16) short Ws[64][40];

  const int tid = threadIdx.x;
  const int m0 = (blockIdx.x & 63) * 64;
  const int nt = blockIdx.x >> 6;        // 0..23
  const int n0g = nt * 64;
  const int sel = n0g >> 9;              // 0=Q 1=K 2=V
  const int nw = n0g & 511;
  const float* Wm = sel == 0 ? wq : (sel == 1 ? wk : wv);
  const float* bias = sel == 0 ? bq : (sel == 1 ? bk : bv);

  const int lrow = tid >> 2;
  const int lcol = (tid & 3) * 8;
  const int wv_ = tid >> 6;
  const int lane = tid & 63;
  const int q4 = lane >> 4;
  const int c = lane & 15;

  f32x4 acc[4];
#pragma unroll
  for (int i = 0; i < 4; i++) acc[i] = f32x4{0.f, 0.f, 0.f, 0.f};

  for (int k0 = 0; k0 < DD; k0 += 32) {
    __syncthreads();
    {
      const float* xp = X + (size_t)(m0 + lrow) * DD + k0 + lcol;
      float4 x0 = *(const float4*)xp;
      float4 x1 = *(const float4*)(xp + 4);
      *(bf16x8*)&Xs[lrow][lcol] = pack8(x0, x1);
      const float* wp = Wm + (size_t)(nw + lrow) * DD + k0 + lcol;
      float4 w0 = *(const float4*)wp;
      float4 w1 = *(const float4*)(wp + 4);
      *(bf16x8*)&Ws[lrow][lcol] = pack8(w0, w1);
    }
    __syncthreads();
    bf16x8 af = *(const bf16x8*)&Xs[16 * wv_ + c][q4 * 8];
#pragma unroll
    for (int ns = 0; ns < 4; ns++) {
      bf16x8 bf = *(const bf16x8*)&Ws[ns * 16 + c][q4 * 8];
      acc[ns] = __builtin_amdgcn_mfma_f32_16x16x32_bf16(af, bf, acc[ns], 0, 0, 0);
    }
  }

#pragma unroll
  for (int ns = 0; ns < 4; ns++) {
    const int n = nw + ns * 16 + c;
    const float bval = bias[n];
    const int hh = n >> 6, d = n & 63;
#pragma unroll
    for (int r = 0; r < 4; r++) {
      const int m = m0 + 16 * wv_ + q4 * 4 + r;
      const int bb = m >> 11, tok = m & 2047;
      const float val = acc[ns][r] + bval;
      if (sel == 2)      vto[((size_t)(bb * HH + hh) * DK + d) * NN + tok] = f2bf(val);
      else if (sel == 1) ko [((size_t)(bb * HH + hh) * NN + tok) * DK + d] = f2bf(val);
      else               qo [((size_t)(bb * HH + hh) * NN + tok) * DK + d] = f2bf(val);
    }
  }
}

// ---------------------------------------------------------------------------
// Flash attention with graph mask + temporal bias.
// Block = 512 thr = 8 waves = (4 heads) x (2 row-halves of a 32-row q tile).
// adj/edge_times tile staged once per block, double-buffered (async split).
// XCD-aware bid decode: each XCD's 32 blocks share one 4-head K/V set (4MB=L2).
// All softmax math in exp2 domain (log2e folded into constants).
// ---------------------------------------------------------------------------
#define LOG2E 1.44269504f
#define SCL2  0.18033688f   /* (1/8) * log2e */

__global__ __launch_bounds__(512) void attn_kernel(
    const short* __restrict__ qt, const short* __restrict__ kt, const short* __restrict__ vtt,
    const int* __restrict__ adj, const float* __restrict__ et,
    const int* __restrict__ ctp, const float* __restrict__ wt, const float* __restrict__ bt,
    short* __restrict__ ao)
{
  __shared__ float tws[2][32][68];            // masked temporal weight (mask -> -1), dbuf
  __shared__ alignas(16) short Ps[8][16][72]; // per-wave P (bf16), padded stride

  const int tid = threadIdx.x;
  const int lane = tid & 63;
  const int w = tid >> 6;          // 0..7
  const int q4 = lane >> 4;
  const int c = lane & 15;

  // XCD-aware decode (bid%8 = XCD under round-robin dispatch)
  const int bid = blockIdx.x;
  const int xcd = bid & 7;
  const int b = xcd >> 2;
  const int hg = (xcd >> 1) & 1;
  const int it = ((xcd & 1) << 5) | (bid >> 3);   // 0..63
  const int i0 = it * 32;

  const int hw = w & 3;
  const int iw16 = (w >> 2) * 16;
  const int h = hg * 4 + hw;
  const int qrow0 = i0 + iw16;

  const float ct = (float)(*ctp);
  const float wth2 = wt[h] * LOG2E;
  const float bth2 = bt[h] * LOG2E;

  const short* qb = qt + ((size_t)(b * HH + h) * NN + qrow0) * DK;
  const short* kb = kt + (size_t)(b * HH + h) * NN * DK;
  const short* vb = vtt + (size_t)(b * HH + h) * DK * NN;
  const int* adjb = adj + (size_t)(b * NN + i0) * NN;
  const float* etb = et + (size_t)(b * NN + i0) * NN;

  // Q fragments (held for the whole j loop); A-row = lane&15
  bf16x8 aq[2];
#pragma unroll
  for (int ks = 0; ks < 2; ks++)
    aq[ks] = *(const bf16x8*)(qb + c * DK + ks * 32 + q4 * 8);

  float m_[4], l_[4];
  f32x4 o[4];
#pragma unroll
  for (int r = 0; r < 4; r++) { m_[r] = -3.0e38f; l_[r] = 0.f; }
#pragma unroll
  for (int ds = 0; ds < 4; ds++) o[ds] = f32x4{0.f, 0.f, 0.f, 0.f};

  // staging geometry: 32 rows x 64 cols, 4 elems/thread
  const int sr = tid >> 4;
  const int sc = (tid & 15) * 4;
  const int* ap_base = adjb + (size_t)sr * NN + sc;
  const float* ep_base = etb + (size_t)sr * NN + sc;

  int4 pa; float4 pe;
  // prologue: load tile 0, write buf 0
  pa = *(const int4*)(ap_base);
  pe = *(const float4*)(ep_base);
  {
    float4 tv;
    tv.x = (pa.x == 0) ? -1.f : exp2f(-0.1f * LOG2E * fmaxf(ct - pe.x, 0.f));
    tv.y = (pa.y == 0) ? -1.f : exp2f(-0.1f * LOG2E * fmaxf(ct - pe.y, 0.f));
    tv.z = (pa.z == 0) ? -1.f : exp2f(-0.1f * LOG2E * fmaxf(ct - pe.z, 0.f));
    tv.w = (pa.w == 0) ? -1.f : exp2f(-0.1f * LOG2E * fmaxf(ct - pe.w, 0.f));
    *(float4*)&tws[0][sr][sc] = tv;
  }
  __syncthreads();

  for (int t = 0; t < 32; t++) {
    const int cur = t & 1;
    const int j0 = t * 64;
    // issue next tile's global loads early (latency hides under compute)
    if (t < 31) {
      pa = *(const int4*)(ap_base + (size_t)(t + 1) * 64);
      pe = *(const float4*)(ep_base + (size_t)(t + 1) * 64);
    }

    // S = Q K^T
    f32x4 s[4];
#pragma unroll
    for (int js = 0; js < 4; js++) s[js] = f32x4{0.f, 0.f, 0.f, 0.f};
#pragma unroll
    for (int ks = 0; ks < 2; ks++) {
      bf16x8 bk[4];
#pragma unroll
      for (int js = 0; js < 4; js++)
        bk[js] = *(const bf16x8*)(kb + (size_t)(j0 + js * 16 + c) * DK + ks * 32 + q4 * 8);
#pragma unroll
      for (int js = 0; js < 4; js++)
        s[js] = __builtin_amdgcn_mfma_f32_16x16x32_bf16(aq[ks], bk[js], s[js], 0, 0, 0);
    }

    // scale + mask + temporal bias (exp2 domain); tile row max
    float tmax[4];
#pragma unroll
    for (int r = 0; r < 4; r++) tmax[r] = -3.0e38f;
#pragma unroll
    for (int js = 0; js < 4; js++)
#pragma unroll
      for (int r = 0; r < 4; r++) {
        const int row = iw16 + q4 * 4 + r;
        const float tv = tws[cur][row][js * 16 + c];
        float sv = s[js][r];
        sv = (tv < 0.f) ? -3.0e38f : fmaf(sv, SCL2, fmaf(tv, wth2, bth2));
        s[js][r] = sv;
        tmax[r] = fmaxf(tmax[r], sv);
      }
#pragma unroll
    for (int r = 0; r < 4; r++) {
#pragma unroll
      for (int off = 1; off < 16; off <<= 1)
        tmax[r] = fmaxf(tmax[r], __shfl_xor(tmax[r], off));
    }

    // online softmax update (all exp2)
    float corr[4], psum[4];
#pragma unroll
    for (int r = 0; r < 4; r++) {
      const float mn = fmaxf(m_[r], tmax[r]);
      corr[r] = exp2f(m_[r] - mn);
      m_[r] = mn;
      psum[r] = 0.f;
    }
#pragma unroll
    for (int js = 0; js < 4; js++)
#pragma unroll
      for (int r = 0; r < 4; r++) {
        const float p = exp2f(s[js][r] - m_[r]);
        psum[r] += p;
        union { float f; unsigned u; } pu; pu.f = p;
        Ps[w][q4 * 4 + r][js * 16 + c] = (short)(pu.u >> 16);  // trunc-to-bf16
      }

    // write next tile's tws while P settles (WAR-safe: other buffer)
    if (t < 31) {
      float4 tv;
      tv.x = (pa.x == 0) ? -1.f : exp2f(-0.1f * LOG2E * fmaxf(ct - pe.x, 0.f));
      tv.y = (pa.y == 0) ? -1.f : exp2f(-0.1f * LOG2E * fmaxf(ct - pe.y, 0.f));
      tv.z = (pa.z == 0) ? -1.f : exp2f(-0.1f * LOG2E * fmaxf(ct - pe.z, 0.f));
      tv.w = (pa.w == 0) ? -1.f : exp2f(-0.1f * LOG2E * fmaxf(ct - pe.w, 0.f));
      *(float4*)&tws[cur ^ 1][sr][sc] = tv;
    }

#pragma unroll
    for (int r = 0; r < 4; r++) {
#pragma unroll
      for (int off = 1; off < 16; off <<= 1)
        psum[r] += __shfl_xor(psum[r], off);
      l_[r] = l_[r] * corr[r] + psum[r];
    }
#pragma unroll
    for (int ds = 0; ds < 4; ds++)
#pragma unroll
      for (int r = 0; r < 4; r++) o[ds][r] *= corr[r];

    // O += P V   (P from per-wave LDS, V^T from global: contiguous 16B frags)
#pragma unroll
    for (int ks = 0; ks < 2; ks++) {
      bf16x8 pf = *(const bf16x8*)&Ps[w][c][ks * 32 + q4 * 8];
      bf16x8 bv[4];
#pragma unroll
      for (int ds = 0; ds < 4; ds++)
        bv[ds] = *(const bf16x8*)(vb + (size_t)(ds * 16 + c) * NN + j0 + ks * 32 + q4 * 8);
#pragma unroll
      for (int ds = 0; ds < 4; ds++)
        o[ds] = __builtin_amdgcn_mfma_f32_16x16x32_bf16(pf, bv[ds], o[ds], 0, 0, 0);
    }

    __syncthreads();
  }

  // epilogue: AO[b][tok][h*64+d] bf16
  float rl[4];
#pragma unroll
  for (int r = 0; r < 4; r++) rl[r] = 1.0f / l_[r];
#pragma unroll
  for (int ds = 0; ds < 4; ds++)
#pragma unroll
    for (int r = 0; r < 4; r++) {
      const int row = qrow0 + q4 * 4 + r;
      const float val = o[ds][r] * rl[r];
      ao[(size_t)(b * NN + row) * DD + h * DK + ds * 16 + c] = f2bf(val);
    }
}

// ---------------------------------------------------------------------------
// GEMM2: out = AO @ wo^T + bo + node_features   (M=4096, N=512, K=512)
// ---------------------------------------------------------------------------
__global__ __launch_bounds__(256) void out_gemm(
    const short* __restrict__ AO, const float* __restrict__ wo, const float* __restrict__ bo,
    const float* __restrict__ nf, float* __restrict__ out)
{
  __shared__ alignas(16) short As[64][40];
  __shared__ alignas(16) short Ws[64][40];

  const int tid = threadIdx.x;
  const int m0 = (blockIdx.x & 63) * 64;
  const int n0 = (blockIdx.x >> 6) * 64;

  const int lrow = tid >> 2;
  const int lcol = (tid & 3) * 8;
  const int wv_ = tid >> 6;
  const int lane = tid & 63;
  const int q4 = lane >> 4;
  const int c = lane & 15;

  f32x4 acc[4];
#pragma unroll
  for (int i = 0; i < 4; i++) acc[i] = f32x4{0.f, 0.f, 0.f, 0.f};

  for (int k0 = 0; k0 < DD; k0 += 32) {
    __syncthreads();
    {
      bf16x8 av = *(const bf16x8*)(AO + (size_t)(m0 + lrow) * DD + k0 + lcol);
      *(bf16x8*)&As[lrow][lcol] = av;
      const float* wp = wo + (size_t)(n0 + lrow) * DD + k0 + lcol;
      float4 w0 = *(const float4*)wp;
      float4 w1 = *(const float4*)(wp + 4);
      *(bf16x8*)&Ws[lrow][lcol] = pack8(w0, w1);
    }
    __syncthreads();
    bf16x8 af = *(const bf16x8*)&As[16 * wv_ + c][q4 * 8];
#pragma unroll
    for (int ns = 0; ns < 4; ns++) {
      bf16x8 bf = *(const bf16x8*)&Ws[ns * 16 + c][q4 * 8];
      acc[ns] = __builtin_amdgcn_mfma_f32_16x16x32_bf16(af, bf, acc[ns], 0, 0, 0);
    }
  }

#pragma unroll
  for (int ns = 0; ns < 4; ns++) {
    const int n = n0 + ns * 16 + c;
    const float bval = bo[n];
#pragma unroll
    for (int r = 0; r < 4; r++) {
      const int m = m0 + 16 * wv_ + q4 * 4 + r;
      out[(size_t)m * DD + n] = acc[ns][r] + bval + nf[(size_t)m * DD + n];
    }
  }
}

extern "C" void kernel_launch(void* const* d_in, const int* in_sizes, int n_in,
                              void* d_out, int out_size, void* d_ws, size_t ws_size,
                              hipStream_t stream) {
  const float* nf  = (const float*)d_in[0];
  const int*   adj = (const int*)d_in[1];
  const float* et  = (const float*)d_in[2];
  const int*   ct  = (const int*)d_in[3];
  const float* wq  = (const float*)d_in[4];
  const float* bq  = (const float*)d_in[5];
  const float* wk  = (const float*)d_in[6];
  const float* bk  = (const float*)d_in[7];
  const float* wv  = (const float*)d_in[8];
  const float* bv  = (const float*)d_in[9];
  const float* wo  = (const float*)d_in[10];
  const float* bo  = (const float*)d_in[11];
  const float* wt  = (const float*)d_in[12];
  const float* bt  = (const float*)d_in[13];

  const size_t SZ = (size_t)BB * HH * NN * DK;  // 2,097,152 elements
  short* q  = (short*)d_ws;
  short* k  = q + SZ;
  short* vt = k + SZ;
  short* ao = vt + SZ;

  qkv_gemm<<<1536, 256, 0, stream>>>(nf, wq, wk, wv, bq, bk, bv, q, k, vt);
  attn_kernel<<<256, 512, 0, stream>>>(q, k, vt, adj, et, ct, wt, bt, ao);
  out_gemm<<<512, 256, 0, stream>>>(ao, wo, bo, nf, (float*)d_out);
}